// Round 1
// baseline (324.753 us; speedup 1.0000x reference)
//
#include <hip/hip_runtime.h>
#include <cmath>

#define BB 8
#define CC 128
#define NN 16384
#define HH 4
#define TN 128
#define NTILES (NN / TN)   // 128
#define NTHR 512
#define KV_SZ 4096         // H * DK * DK

// ---------------------------------------------------------------------------
// Register-tiled fp32 GEMM: out[co][n] = sum_c Wt[c][co] * Xs[c][n]
// Thread (tx,ty): tx = tid>>4 (0..31, 4 positions each), ty = tid&15 (8 ch each)
// ---------------------------------------------------------------------------
__device__ __forceinline__ void gemm128(const float* __restrict__ Xs,
                                        const float* __restrict__ Wt,
                                        const int tx, const int ty,
                                        float acc[8][4])
{
#pragma unroll
  for (int r = 0; r < 8; ++r)
#pragma unroll
    for (int j = 0; j < 4; ++j) acc[r][j] = 0.0f;

#pragma unroll 2
  for (int c = 0; c < CC; ++c) {
    const float4 xv = *reinterpret_cast<const float4*>(&Xs[c * TN + tx * 4]);
    const float4 w0 = *reinterpret_cast<const float4*>(&Wt[c * CC + ty * 8]);
    const float4 w1 = *reinterpret_cast<const float4*>(&Wt[c * CC + ty * 8 + 4]);
    const float xj[4] = {xv.x, xv.y, xv.z, xv.w};
    const float wr[8] = {w0.x, w0.y, w0.z, w0.w, w1.x, w1.y, w1.z, w1.w};
#pragma unroll
    for (int r = 0; r < 8; ++r)
#pragma unroll
      for (int j = 0; j < 4; ++j)
        acc[r][j] = fmaf(wr[r], xj[j], acc[r][j]);
  }
}

// Per-head LayerNorm over 32 channels. Channels of one head live in 4 adjacent
// lanes (ty%4 = lane bits [1:0]), 8 channels per lane -> shfl_xor 1,2 reduce.
__device__ __forceinline__ void ln32(float acc[8][4],
                                     const float* __restrict__ g,
                                     const float* __restrict__ be,
                                     const int ty)
{
  float gr[8], br[8];
#pragma unroll
  for (int r = 0; r < 8; ++r) { gr[r] = g[ty * 8 + r]; br[r] = be[ty * 8 + r]; }
#pragma unroll
  for (int j = 0; j < 4; ++j) {
    float s = 0.0f, ss = 0.0f;
#pragma unroll
    for (int r = 0; r < 8; ++r) { s += acc[r][j]; ss += acc[r][j] * acc[r][j]; }
    s += __shfl_xor(s, 1);  ss += __shfl_xor(ss, 1);
    s += __shfl_xor(s, 2);  ss += __shfl_xor(ss, 2);
    const float mu   = s * (1.0f / 32.0f);
    const float var  = ss * (1.0f / 32.0f) - mu * mu;
    const float rstd = rsqrtf(var + 1e-5f);
#pragma unroll
    for (int r = 0; r < 8; ++r)
      acc[r][j] = (acc[r][j] - mu) * rstd * gr[r] + br[r];
  }
}

// ---------------------------------------------------------------------------
// K0: transpose Wq,Wk,Wv,Wo (128x128 each) into ws: WT[c][co] = W[co][c]
// ---------------------------------------------------------------------------
__global__ void k_transpose(const float* __restrict__ Wq, const float* __restrict__ Wk,
                            const float* __restrict__ Wv, const float* __restrict__ Wo,
                            float* __restrict__ WT)
{
  const float* src = (blockIdx.y == 0) ? Wq : (blockIdx.y == 1) ? Wk
                   : (blockIdx.y == 2) ? Wv : Wo;
  float* dst = WT + (size_t)blockIdx.y * CC * CC;
  for (int idx = blockIdx.x * 256 + threadIdx.x; idx < CC * CC; idx += gridDim.x * 256) {
    const int c = idx >> 7, co = idx & 127;
    dst[idx] = src[co * CC + c];
  }
}

// ---------------------------------------------------------------------------
// K1: per (b, tile): k = LN(Wk x + bk), v = LN(Wv x + bv); partial kv = sum_n k v^T
// LDS: buf0 = Xs[C][TN] -> kS[n][c]; buf1 = Wt[C][C] -> vS[n][c]   (128 KB)
// ---------------------------------------------------------------------------
__global__ __launch_bounds__(NTHR)
void k_proj_kv(const float* __restrict__ x,
               const float* __restrict__ WTk, const float* __restrict__ bk,
               const float* __restrict__ WTv, const float* __restrict__ bv,
               const float* __restrict__ gK, const float* __restrict__ bK,
               const float* __restrict__ gV, const float* __restrict__ bV,
               float* __restrict__ kvp)
{
  extern __shared__ __align__(16) float lds[];
  float* buf0 = lds;             // 16384 floats
  float* buf1 = lds + CC * TN;   // 16384 floats

  const int tile = blockIdx.x, b = blockIdx.y;
  const int n0  = tile * TN;
  const int tid = threadIdx.x;
  const int tx = tid >> 4, ty = tid & 15;

  {
    const float* xb = x + (size_t)b * CC * NN;
    for (int idx = tid; idx < CC * (TN / 4); idx += NTHR) {
      const int c = idx >> 5, f = idx & 31;
      *reinterpret_cast<float4*>(&buf0[c * TN + f * 4]) =
          *reinterpret_cast<const float4*>(&xb[(size_t)c * NN + n0 + f * 4]);
    }
  }
  for (int idx = tid; idx < CC * CC / 4; idx += NTHR)
    *reinterpret_cast<float4*>(&buf1[idx * 4]) =
        *reinterpret_cast<const float4*>(&WTk[idx * 4]);
  __syncthreads();

  float kacc[8][4];
  gemm128(buf0, buf1, tx, ty, kacc);
#pragma unroll
  for (int r = 0; r < 8; ++r) {
    const float bias = bk[ty * 8 + r];
#pragma unroll
    for (int j = 0; j < 4; ++j) kacc[r][j] += bias;
  }
  __syncthreads();   // done reading Wt(K)

  for (int idx = tid; idx < CC * CC / 4; idx += NTHR)
    *reinterpret_cast<float4*>(&buf1[idx * 4]) =
        *reinterpret_cast<const float4*>(&WTv[idx * 4]);
  ln32(kacc, gK, bK, ty);          // register-only, overlaps the load
  __syncthreads();

  float vacc[8][4];
  gemm128(buf0, buf1, tx, ty, vacc);
#pragma unroll
  for (int r = 0; r < 8; ++r) {
    const float bias = bv[ty * 8 + r];
#pragma unroll
    for (int j = 0; j < 4; ++j) vacc[r][j] += bias;
  }
  ln32(vacc, gV, bV, ty);
  __syncthreads();   // done reading Xs and Wt(V)

  // stage k,v as [n][c] for the kv outer-product pass
#pragma unroll
  for (int j = 0; j < 4; ++j) {
    const int n = tx * 4 + j;
    *reinterpret_cast<float4*>(&buf0[n * CC + ty * 8]) =
        make_float4(kacc[0][j], kacc[1][j], kacc[2][j], kacc[3][j]);
    *reinterpret_cast<float4*>(&buf0[n * CC + ty * 8 + 4]) =
        make_float4(kacc[4][j], kacc[5][j], kacc[6][j], kacc[7][j]);
    *reinterpret_cast<float4*>(&buf1[n * CC + ty * 8]) =
        make_float4(vacc[0][j], vacc[1][j], vacc[2][j], vacc[3][j]);
    *reinterpret_cast<float4*>(&buf1[n * CC + ty * 8 + 4]) =
        make_float4(vacc[4][j], vacc[5][j], vacc[6][j], vacc[7][j]);
  }
  __syncthreads();

  // kv[h][d][e] partial: thread -> h2 = tid>>7, d = (tid>>2)&31, eg = tid&3
  const int h2 = tid >> 7, d = (tid >> 2) & 31, eg = tid & 3;
  float a8[8] = {0, 0, 0, 0, 0, 0, 0, 0};
#pragma unroll 2
  for (int n = 0; n < TN; ++n) {
    const float kd = buf0[n * CC + h2 * 32 + d];
    const float4 v0 = *reinterpret_cast<const float4*>(&buf1[n * CC + h2 * 32 + eg * 8]);
    const float4 v1 = *reinterpret_cast<const float4*>(&buf1[n * CC + h2 * 32 + eg * 8 + 4]);
    a8[0] = fmaf(kd, v0.x, a8[0]);  a8[1] = fmaf(kd, v0.y, a8[1]);
    a8[2] = fmaf(kd, v0.z, a8[2]);  a8[3] = fmaf(kd, v0.w, a8[3]);
    a8[4] = fmaf(kd, v1.x, a8[4]);  a8[5] = fmaf(kd, v1.y, a8[5]);
    a8[6] = fmaf(kd, v1.z, a8[6]);  a8[7] = fmaf(kd, v1.w, a8[7]);
  }
  float* o = kvp + ((size_t)b * NTILES + tile) * KV_SZ + tid * 8;
  *reinterpret_cast<float4*>(o)     = make_float4(a8[0], a8[1], a8[2], a8[3]);
  *reinterpret_cast<float4*>(o + 4) = make_float4(a8[4], a8[5], a8[6], a8[7]);
}

// ---------------------------------------------------------------------------
// K2: kv[b][e] = scale * sum_t kvp[b][t][e]   (fixed order -> deterministic)
// ---------------------------------------------------------------------------
__global__ void k_reduce_kv(const float* __restrict__ kvp, float* __restrict__ kv,
                            const float scale)
{
  const int idx = blockIdx.x * 256 + threadIdx.x;   // < BB*KV_SZ
  const int b = idx >> 12;
  const float* p = kvp + (size_t)b * NTILES * KV_SZ + (idx & (KV_SZ - 1));
  float s = 0.0f;
  for (int t = 0; t < NTILES; ++t) s += p[(size_t)t * KV_SZ];
  kv[idx] = s * scale;
}

// ---------------------------------------------------------------------------
// K4: q = Wq x + bq; A[c'] = sum_d q[h,d] kv[h][d][e]; out = Wo A + bo
// LDS: buf0: Xs -> qs[c][n] -> WtO ; buf1: WtQ -> As[c'][n] ; kvs 16KB  (144 KB)
// ---------------------------------------------------------------------------
__global__ __launch_bounds__(NTHR)
void k_attn_out(const float* __restrict__ x,
                const float* __restrict__ WTq, const float* __restrict__ bq,
                const float* __restrict__ kv,
                const float* __restrict__ WTo, const float* __restrict__ bo,
                float* __restrict__ out)
{
  extern __shared__ __align__(16) float lds[];
  float* buf0 = lds;
  float* buf1 = lds + CC * TN;
  float* kvs  = lds + 2 * CC * TN;

  const int tile = blockIdx.x, b = blockIdx.y;
  const int n0  = tile * TN;
  const int tid = threadIdx.x;
  const int tx = tid >> 4, ty = tid & 15;
  const int h = ty >> 2, e0 = (ty & 3) * 8;

  {
    const float* xb = x + (size_t)b * CC * NN;
    for (int idx = tid; idx < CC * (TN / 4); idx += NTHR) {
      const int c = idx >> 5, f = idx & 31;
      *reinterpret_cast<float4*>(&buf0[c * TN + f * 4]) =
          *reinterpret_cast<const float4*>(&xb[(size_t)c * NN + n0 + f * 4]);
    }
  }
  for (int idx = tid; idx < CC * CC / 4; idx += NTHR)
    *reinterpret_cast<float4*>(&buf1[idx * 4]) =
        *reinterpret_cast<const float4*>(&WTq[idx * 4]);
  for (int idx = tid; idx < KV_SZ / 4; idx += NTHR)
    *reinterpret_cast<float4*>(&kvs[idx * 4]) =
        *reinterpret_cast<const float4*>(&kv[(size_t)b * KV_SZ + idx * 4]);
  __syncthreads();

  float qacc[8][4];
  gemm128(buf0, buf1, tx, ty, qacc);
#pragma unroll
  for (int r = 0; r < 8; ++r) {
    const float bias = bq[ty * 8 + r];
#pragma unroll
    for (int j = 0; j < 4; ++j) qacc[r][j] += bias;
  }
  __syncthreads();   // all reads of Xs (buf0) done

  // qs = buf0 as [c][n]
#pragma unroll
  for (int r = 0; r < 8; ++r)
    *reinterpret_cast<float4*>(&buf0[(ty * 8 + r) * TN + tx * 4]) =
        make_float4(qacc[r][0], qacc[r][1], qacc[r][2], qacc[r][3]);
  __syncthreads();

  // A[c'=8ty+r][n=4tx+j] = sum_d qs[32h+d][n] * kv[h][d][e0+r]
  float aacc[8][4];
#pragma unroll
  for (int r = 0; r < 8; ++r)
#pragma unroll
    for (int j = 0; j < 4; ++j) aacc[r][j] = 0.0f;
  const float* kvh = &kvs[h * 1024];
#pragma unroll 2
  for (int d = 0; d < 32; ++d) {
    const float4 q4 = *reinterpret_cast<const float4*>(&buf0[(h * 32 + d) * TN + tx * 4]);
    const float4 k0 = *reinterpret_cast<const float4*>(&kvh[d * 32 + e0]);
    const float4 k1 = *reinterpret_cast<const float4*>(&kvh[d * 32 + e0 + 4]);
    const float qj[4] = {q4.x, q4.y, q4.z, q4.w};
    const float ke[8] = {k0.x, k0.y, k0.z, k0.w, k1.x, k1.y, k1.z, k1.w};
#pragma unroll
    for (int r = 0; r < 8; ++r)
#pragma unroll
      for (int j = 0; j < 4; ++j)
        aacc[r][j] = fmaf(ke[r], qj[j], aacc[r][j]);
  }
  // A -> buf1 (WtQ is dead since the sync after the q-GEMM)
#pragma unroll
  for (int r = 0; r < 8; ++r)
    *reinterpret_cast<float4*>(&buf1[(ty * 8 + r) * TN + tx * 4]) =
        make_float4(aacc[r][0], aacc[r][1], aacc[r][2], aacc[r][3]);
  __syncthreads();   // all reads of qs (buf0) done, A fully staged

  for (int idx = tid; idx < CC * CC / 4; idx += NTHR)
    *reinterpret_cast<float4*>(&buf0[idx * 4]) =
        *reinterpret_cast<const float4*>(&WTo[idx * 4]);
  __syncthreads();

  float oacc[8][4];
  gemm128(buf1, buf0, tx, ty, oacc);   // Xs = A, Wt = WoT

  float* ob = out + (size_t)b * CC * NN;
#pragma unroll
  for (int r = 0; r < 8; ++r) {
    const float bias = bo[ty * 8 + r];
    const float4 v = make_float4(oacc[r][0] + bias, oacc[r][1] + bias,
                                 oacc[r][2] + bias, oacc[r][3] + bias);
    *reinterpret_cast<float4*>(&ob[(size_t)(ty * 8 + r) * NN + n0 + tx * 4]) = v;
  }
}

// ---------------------------------------------------------------------------
extern "C" void kernel_launch(void* const* d_in, const int* in_sizes, int n_in,
                              void* d_out, int out_size, void* d_ws, size_t ws_size,
                              hipStream_t stream)
{
  const float* x  = (const float*)d_in[0];
  const float* Wq = (const float*)d_in[1];
  const float* bq = (const float*)d_in[2];
  const float* Wk = (const float*)d_in[3];
  const float* bk = (const float*)d_in[4];
  const float* Wv = (const float*)d_in[5];
  const float* bv = (const float*)d_in[6];
  const float* gK = (const float*)d_in[7];
  const float* bK = (const float*)d_in[8];
  const float* gV = (const float*)d_in[9];
  const float* bV = (const float*)d_in[10];
  const float* Wo = (const float*)d_in[11];
  const float* bo = (const float*)d_in[12];
  float* out = (float*)d_out;

  float* ws  = (float*)d_ws;
  float* kvp = ws;                                    // 8*128*4096 floats (16 MB)
  float* kv  = kvp + (size_t)BB * NTILES * KV_SZ;     // 8*4096 floats
  float* WT  = kv + (size_t)BB * KV_SZ;               // 4*16384 floats
  float* WTq = WT;
  float* WTk = WT + 16384;
  float* WTv = WT + 32768;
  float* WTo = WT + 49152;

  (void)hipFuncSetAttribute(reinterpret_cast<const void*>(k_proj_kv),
                            hipFuncAttributeMaxDynamicSharedMemorySize, 131072);
  (void)hipFuncSetAttribute(reinterpret_cast<const void*>(k_attn_out),
                            hipFuncAttributeMaxDynamicSharedMemorySize, 147456);

  k_transpose<<<dim3(16, 4), 256, 0, stream>>>(Wq, Wk, Wv, Wo, WT);

  k_proj_kv<<<dim3(NTILES, BB), NTHR, 131072, stream>>>(
      x, WTk, bk, WTv, bv, gK, bK, gV, bV, kvp);

  const float scale = 1.0f / (sqrtf(32.0f) * 16384.0f);
  k_reduce_kv<<<dim3((BB * KV_SZ) / 256), 256, 0, stream>>>(kvp, kv, scale);

  k_attn_out<<<dim3(NTILES, BB), NTHR, 147456, stream>>>(
      x, WTq, bq, kv, WTo, bo, out);
}

// Round 2
// 120.840 us; speedup vs baseline: 2.6875x; 2.6875x over previous
//
#include <hip/hip_runtime.h>
#include <cmath>

#define BB 8
#define CC 128
#define NN 16384
#define HH 4
#define TN 64                    // n positions per tile
#define TPB 4                    // tiles per block in pass1
#define NT_TOTAL (NN / TN)       // 256
#define P1_GROUPS (NT_TOTAL / TPB) // 64
#define SLOTS (P1_GROUPS * 2)    // kv partial slots per batch (2 halves/block)

typedef __attribute__((ext_vector_type(8))) short bf16x8;
typedef __attribute__((ext_vector_type(4))) float f32x4;

#define MFMA(a, b, c) __builtin_amdgcn_mfma_f32_16x16x32_bf16(a, b, c, 0, 0, 0)

// fp32 -> bf16 (RNE)
__device__ __forceinline__ unsigned short f2b(float f) {
  union { float f; unsigned u; } v; v.f = f;
  unsigned r = v.u + 0x7FFFu + ((v.u >> 16) & 1u);
  return (unsigned short)(r >> 16);
}

// XT/QS/AS layout: [n][c] bf16, 256 B/row, XOR-swizzle on 16B blocks (8 bf16)
__device__ __forceinline__ int xt_byte(int n, int c) {
  return n * 256 + ((((c >> 3) ^ (n & 15)) << 4) | ((c & 7) << 1));
}
// KT/VT layout: [c][n] bf16, 144 B/row stride (n<=64 used), XOR-swizzle on 16B blocks
__device__ __forceinline__ int kt_byte(int c, int n) {
  return c * 144 + ((((n >> 3) ^ (c & 7)) << 4) | ((n & 7) << 1));
}

// Transpose one 128c x 64n fp32 tile of x into XT (bf16, swizzled [n][c]).
__device__ __forceinline__ void stage_xt(char* XT, const float* __restrict__ x,
                                         int b, int n0, int tid) {
#pragma unroll
  for (int rr = 0; rr < 2; ++rr) {
    const int c2 = (tid >> 4) + rr * 32;   // c-pair index 0..63
    const int nq = tid & 15;
    const float* xr = x + ((size_t)b * CC + 2 * c2) * NN + n0 + nq * 4;
    const float4 a0 = *(const float4*)xr;
    const float4 a1 = *(const float4*)(xr + NN);
    const float va0[4] = {a0.x, a0.y, a0.z, a0.w};
    const float va1[4] = {a1.x, a1.y, a1.z, a1.w};
#pragma unroll
    for (int j = 0; j < 4; ++j) {
      const int n = nq * 4 + j, c = 2 * c2;
      const unsigned pk = (unsigned)f2b(va0[j]) | ((unsigned)f2b(va1[j]) << 16);
      *(unsigned*)(XT + xt_byte(n, c)) = pk;
    }
  }
}

// ---------------------------------------------------------------------------
// K0: convert Wq,Wk,Wv,Wo fp32[128][128] -> bf16 (same layout)
// ---------------------------------------------------------------------------
__global__ void k_prep(const float* __restrict__ Wq, const float* __restrict__ Wk,
                       const float* __restrict__ Wv, const float* __restrict__ Wo,
                       unsigned short* __restrict__ Wb) {
  const int idx = blockIdx.x * 256 + threadIdx.x;   // < 65536
  const int which = idx >> 14;
  const float* src = (which == 0) ? Wq : (which == 1) ? Wk : (which == 2) ? Wv : Wo;
  Wb[idx] = f2b(src[idx & 16383]);
}

// ---------------------------------------------------------------------------
// K1: K,V projection + per-head LN + partial K^T V   (MFMA)
// waves: proj phase (head = w>>1, proj = w&1); kv phase (head = w>>1, half = w&1)
// ---------------------------------------------------------------------------
__global__ __launch_bounds__(512, 4)
void k_pass1(const float* __restrict__ x,
             const unsigned short* __restrict__ Wkb, const unsigned short* __restrict__ Wvb,
             const float* __restrict__ bk, const float* __restrict__ bv,
             const float* __restrict__ gK, const float* __restrict__ bK,
             const float* __restrict__ gV, const float* __restrict__ bV,
             float* __restrict__ kvp) {
  extern __shared__ char lds[];
  char* XT = lds;               // 16384 B
  char* KT = lds + 16384;       // 18432 B
  char* VT = lds + 34816;       // 18432 B

  const int tid = threadIdx.x;
  const int lane = tid & 63;
  const int w = tid >> 6;
  const int b = blockIdx.y;
  const int l15 = lane & 15, l4 = lane >> 4;

  const int ph = w >> 1;        // head (proj phase)
  const int pp = w & 1;         // 0=K, 1=V
  const int kh = w >> 1, khalf = w & 1;   // kv phase roles

  // W fragments in registers: A-operand, row = l15 (c_out), k = ks*32 + l4*8 + j
  const unsigned short* Wsrc = pp ? Wvb : Wkb;
  bf16x8 wf[2][4];
#pragma unroll
  for (int mf = 0; mf < 2; ++mf)
#pragma unroll
    for (int ks = 0; ks < 4; ++ks)
      wf[mf][ks] = *(const bf16x8*)(Wsrc + (ph * 32 + mf * 16 + l15) * 128 + ks * 32 + l4 * 8);

  // bias / gamma / beta for this lane's channels: c_local = mf*16 + l4*4 + r
  float bias[2][4], gam[2][4], bet[2][4];
  {
    const float* bsrc = pp ? bv : bk;
    const float* gsrc = pp ? gV : gK;
    const float* esrc = pp ? bV : bK;
#pragma unroll
    for (int mf = 0; mf < 2; ++mf)
#pragma unroll
      for (int r = 0; r < 4; ++r) {
        const int cg = ph * 32 + mf * 16 + l4 * 4 + r;
        bias[mf][r] = bsrc[cg]; gam[mf][r] = gsrc[cg]; bet[mf][r] = esrc[cg];
      }
  }

  f32x4 kvacc[2][2];
#pragma unroll
  for (int i = 0; i < 2; ++i)
#pragma unroll
    for (int j = 0; j < 2; ++j) kvacc[i][j] = (f32x4){0.f, 0.f, 0.f, 0.f};

  for (int t = 0; t < TPB; ++t) {
    const int n0 = (blockIdx.x * TPB + t) * TN;

    // Phase A: x -> XT (bf16 transposed, swizzled)
    stage_xt(XT, x, b, n0, tid);
    __syncthreads();

    // Phase B: projection GEMM, D[c][n] = W * X
    f32x4 acc[2][4];
#pragma unroll
    for (int mf = 0; mf < 2; ++mf)
#pragma unroll
      for (int nf = 0; nf < 4; ++nf) acc[mf][nf] = (f32x4){0.f, 0.f, 0.f, 0.f};
#pragma unroll
    for (int ks = 0; ks < 4; ++ks)
#pragma unroll
      for (int nf = 0; nf < 4; ++nf) {
        const int n = nf * 16 + l15;
        const bf16x8 xf = *(const bf16x8*)(XT + n * 256 + (((ks * 4 + l4) ^ (n & 15)) << 4));
        acc[0][nf] = MFMA(wf[0][ks], xf, acc[0][nf]);
        acc[1][nf] = MFMA(wf[1][ks], xf, acc[1][nf]);
      }
    // bias
#pragma unroll
    for (int mf = 0; mf < 2; ++mf)
#pragma unroll
      for (int nf = 0; nf < 4; ++nf)
#pragma unroll
        for (int r = 0; r < 4; ++r) acc[mf][nf][r] += bias[mf][r];
    // per-head LayerNorm (32 channels, per position n) + stage bf16 to KT/VT
    char* DST = pp ? VT : KT;
#pragma unroll
    for (int nf = 0; nf < 4; ++nf) {
      float s = 0.f, ss = 0.f;
#pragma unroll
      for (int mf = 0; mf < 2; ++mf)
#pragma unroll
        for (int r = 0; r < 4; ++r) { const float v = acc[mf][nf][r]; s += v; ss += v * v; }
      s += __shfl_xor(s, 16); ss += __shfl_xor(ss, 16);
      s += __shfl_xor(s, 32); ss += __shfl_xor(ss, 32);
      const float mu = s * (1.f / 32.f);
      const float var = ss * (1.f / 32.f) - mu * mu;
      const float rstd = rsqrtf(var + 1e-5f);
      const int n = nf * 16 + l15;
#pragma unroll
      for (int mf = 0; mf < 2; ++mf)
#pragma unroll
        for (int r = 0; r < 4; ++r) {
          const float a = rstd * gam[mf][r];
          const float vv = (acc[mf][nf][r] - mu) * a + bet[mf][r];
          const int c = ph * 32 + mf * 16 + l4 * 4 + r;
          *(unsigned short*)(DST + kt_byte(c, n)) = f2b(vv);
        }
    }
    __syncthreads();

    // Phase C: kv partial += K^T V over this wave's 32-n half
#pragma unroll
    for (int mf = 0; mf < 2; ++mf) {
      const int ck = kh * 32 + mf * 16 + l15;
      const bf16x8 ka = *(const bf16x8*)(KT + ck * 144 + (((khalf * 4 + l4) ^ (ck & 7)) << 4));
#pragma unroll
      for (int ef = 0; ef < 2; ++ef) {
        const int cv = kh * 32 + ef * 16 + l15;
        const bf16x8 vb = *(const bf16x8*)(VT + cv * 144 + (((khalf * 4 + l4) ^ (cv & 7)) << 4));
        kvacc[mf][ef] = MFMA(ka, vb, kvacc[mf][ef]);
      }
    }
    // no barrier needed here: next A writes XT only; post-A barrier orders C vs next B
  }

  // write kv partials: [b][slot][h][d*32+e] fp32
  const int slot = blockIdx.x * 2 + khalf;
  float* o = kvp + (((size_t)b * SLOTS + slot) * HH + kh) * 1024;
#pragma unroll
  for (int mf = 0; mf < 2; ++mf)
#pragma unroll
    for (int ef = 0; ef < 2; ++ef)
#pragma unroll
      for (int r = 0; r < 4; ++r) {
        const int d = mf * 16 + l4 * 4 + r, e = ef * 16 + l15;
        o[d * 32 + e] = kvacc[mf][ef][r];
      }
}

// ---------------------------------------------------------------------------
// K2: kv reduce over 128 slots (fixed order), scale, store transposed bf16
//     kvT[b][h][e][d]
// ---------------------------------------------------------------------------
__global__ void k_reduce(const float* __restrict__ kvp, unsigned short* __restrict__ kvT,
                         const float scale) {
  __shared__ float red[4][64];
  const int tid = threadIdx.x;
  const int part = tid >> 6;           // wave id 0..3
  const int sl = tid & 63;
  const int ot = blockIdx.x * 64 + sl; // output element: b*4096 + h*1024 + d*32 + e
  const int b = ot >> 12, rem = ot & 4095;
  const float* p = kvp + (size_t)b * SLOTS * (HH * 1024) + rem;
  float s = 0.f;
#pragma unroll 8
  for (int t2 = 0; t2 < SLOTS / 4; ++t2) s += p[(size_t)(part * (SLOTS / 4) + t2) * 4096];
  red[part][sl] = s;
  __syncthreads();
  if (tid < 64) {
    const float tot = (red[0][tid] + red[1][tid] + red[2][tid] + red[3][tid]) * scale;
    const int o2 = blockIdx.x * 64 + tid;
    const int b2 = o2 >> 12, r2 = o2 & 4095;
    const int h = r2 >> 10, d = (r2 >> 5) & 31, e = r2 & 31;
    kvT[(((size_t)b2 * HH + h) * 32 + e) * 32 + d] = f2b(tot);
  }
}

// ---------------------------------------------------------------------------
// K3: Q proj + attn (q @ kv) + output GEMM + bias, coalesced fp32 store
// ---------------------------------------------------------------------------
__global__ __launch_bounds__(512, 4)
void k_pass2(const float* __restrict__ x,
             const unsigned short* __restrict__ Wqb, const float* __restrict__ bq,
             const unsigned short* __restrict__ kvT,
             const unsigned short* __restrict__ Wob, const float* __restrict__ bo,
             float* __restrict__ out) {
  extern __shared__ char lds[];
  char* XT = lds;            // 16384
  char* QS = lds + 16384;    // 16384  q as [n][c]
  char* AS = lds + 32768;    // 16384  attn out as [n][c']

  const int tid = threadIdx.x;
  const int lane = tid & 63;
  const int w = tid >> 6;
  const int b = blockIdx.y;
  const int n0 = blockIdx.x * TN;
  const int l15 = lane & 15, l4 = lane >> 4;
  const int h = w >> 1, half = w & 1;

  // kv A-fragments (row = e, k = d) from global bf16 kvT[b][h][e][d]
  bf16x8 kvf[2];
#pragma unroll
  for (int mf = 0; mf < 2; ++mf)
    kvf[mf] = *(const bf16x8*)(kvT + (((size_t)b * HH + h) * 32 + mf * 16 + l15) * 32 + l4 * 8);
  // Wq / Wo fragments for this wave's 16-channel slice
  bf16x8 wq[4], wo[4];
#pragma unroll
  for (int ks = 0; ks < 4; ++ks) {
    wq[ks] = *(const bf16x8*)(Wqb + (w * 16 + l15) * 128 + ks * 32 + l4 * 8);
    wo[ks] = *(const bf16x8*)(Wob + (w * 16 + l15) * 128 + ks * 32 + l4 * 8);
  }
  float bq_r[4], bo_r[4];
#pragma unroll
  for (int r = 0; r < 4; ++r) {
    bq_r[r] = bq[w * 16 + l4 * 4 + r];
    bo_r[r] = bo[w * 16 + l4 * 4 + r];
  }

  // Phase A: x -> XT
  stage_xt(XT, x, b, n0, tid);
  __syncthreads();

  // Phase B: q-GEMM, D[c][n], c-slice = w*16
  f32x4 qa[4];
#pragma unroll
  for (int nf = 0; nf < 4; ++nf) qa[nf] = (f32x4){0.f, 0.f, 0.f, 0.f};
#pragma unroll
  for (int ks = 0; ks < 4; ++ks)
#pragma unroll
    for (int nf = 0; nf < 4; ++nf) {
      const int n = nf * 16 + l15;
      const bf16x8 xf = *(const bf16x8*)(XT + n * 256 + (((ks * 4 + l4) ^ (n & 15)) << 4));
      qa[nf] = MFMA(wq[ks], xf, qa[nf]);
    }
  // bias + stage q to QS[n][c] (pack 4 consecutive c rows -> b64)
#pragma unroll
  for (int nf = 0; nf < 4; ++nf) {
    const int n = nf * 16 + l15;
    const int c0 = w * 16 + l4 * 4;
    unsigned long long pk = 0;
#pragma unroll
    for (int r = 0; r < 4; ++r)
      pk |= (unsigned long long)f2b(qa[nf][r] + bq_r[r]) << (16 * r);
    *(unsigned long long*)(QS + n * 256 + (((c0 >> 3) ^ (n & 15)) << 4) + ((c0 & 7) << 1)) = pk;
  }
  __syncthreads();

  // Phase C: attn D[e][n] = kv^T(as A) * q(as B), per (head, n-half)
  f32x4 aa[2][2];
#pragma unroll
  for (int i = 0; i < 2; ++i)
#pragma unroll
    for (int j = 0; j < 2; ++j) aa[i][j] = (f32x4){0.f, 0.f, 0.f, 0.f};
  bf16x8 qf[2];
#pragma unroll
  for (int nf = 0; nf < 2; ++nf) {
    const int n = half * 32 + nf * 16 + l15;
    const int cq = h * 32 + l4 * 8;   // d-chunk
    qf[nf] = *(const bf16x8*)(QS + n * 256 + ((((cq >> 3)) ^ (n & 15)) << 4));
  }
#pragma unroll
  for (int mf = 0; mf < 2; ++mf)
#pragma unroll
    for (int nf = 0; nf < 2; ++nf) aa[mf][nf] = MFMA(kvf[mf], qf[nf], aa[mf][nf]);
  // stage attn out to AS[n][c'] (pack 4 consecutive e rows)
#pragma unroll
  for (int mf = 0; mf < 2; ++mf)
#pragma unroll
    for (int nf = 0; nf < 2; ++nf) {
      const int n = half * 32 + nf * 16 + l15;
      const int e0 = h * 32 + mf * 16 + l4 * 4;
      unsigned long long pk = 0;
#pragma unroll
      for (int r = 0; r < 4; ++r)
        pk |= (unsigned long long)f2b(aa[mf][nf][r]) << (16 * r);
      *(unsigned long long*)(AS + n * 256 + (((e0 >> 3) ^ (n & 15)) << 4) + ((e0 & 7) << 1)) = pk;
    }
  __syncthreads();

  // Phase D: out-GEMM, D[c_out][n], c_out-slice = w*16
  f32x4 oa[4];
#pragma unroll
  for (int nf = 0; nf < 4; ++nf) oa[nf] = (f32x4){0.f, 0.f, 0.f, 0.f};
#pragma unroll
  for (int ks = 0; ks < 4; ++ks)
#pragma unroll
    for (int nf = 0; nf < 4; ++nf) {
      const int n = nf * 16 + l15;
      const bf16x8 af = *(const bf16x8*)(AS + n * 256 + (((ks * 4 + l4) ^ (n & 15)) << 4));
      oa[nf] = MFMA(wo[ks], af, oa[nf]);
    }
  float* ob = out + (size_t)b * CC * NN;
#pragma unroll
  for (int nf = 0; nf < 4; ++nf)
#pragma unroll
    for (int r = 0; r < 4; ++r) {
      const int c = w * 16 + l4 * 4 + r;
      ob[(size_t)c * NN + n0 + nf * 16 + l15] = oa[nf][r] + bo_r[r];
    }
}

// ---------------------------------------------------------------------------
extern "C" void kernel_launch(void* const* d_in, const int* in_sizes, int n_in,
                              void* d_out, int out_size, void* d_ws, size_t ws_size,
                              hipStream_t stream) {
  const float* x  = (const float*)d_in[0];
  const float* Wq = (const float*)d_in[1];
  const float* bq = (const float*)d_in[2];
  const float* Wk = (const float*)d_in[3];
  const float* bk = (const float*)d_in[4];
  const float* Wv = (const float*)d_in[5];
  const float* bv = (const float*)d_in[6];
  const float* gK = (const float*)d_in[7];
  const float* bK = (const float*)d_in[8];
  const float* gV = (const float*)d_in[9];
  const float* bV = (const float*)d_in[10];
  const float* Wo = (const float*)d_in[11];
  const float* bo = (const float*)d_in[12];
  float* out = (float*)d_out;

  char* ws = (char*)d_ws;
  float* kvp = (float*)ws;                                   // 8*128*4096 f32 = 16 MB
  unsigned short* kvTb = (unsigned short*)(ws + (size_t)BB * SLOTS * HH * 1024 * 4); // 64 KB
  unsigned short* Wb = kvTb + (size_t)BB * HH * 1024;        // 128 KB
  const unsigned short* Wqb = Wb;
  const unsigned short* Wkb = Wb + 16384;
  const unsigned short* Wvb = Wb + 32768;
  const unsigned short* Wob = Wb + 49152;

  (void)hipFuncSetAttribute(reinterpret_cast<const void*>(k_pass1),
                            hipFuncAttributeMaxDynamicSharedMemorySize, 53248);
  (void)hipFuncSetAttribute(reinterpret_cast<const void*>(k_pass2),
                            hipFuncAttributeMaxDynamicSharedMemorySize, 49152);

  k_prep<<<256, 256, 0, stream>>>(Wq, Wk, Wv, Wo, Wb);

  k_pass1<<<dim3(P1_GROUPS, BB), 512, 53248, stream>>>(
      x, Wkb, Wvb, bk, bv, gK, bK, gV, bV, kvp);

  const float scale = 1.0f / (5.65685424949238f * 16384.0f);  // 1/(sqrt(32)*N)
  k_reduce<<<(BB * 4096) / 64, 256, 0, stream>>>(kvp, kvTb, scale);

  k_pass2<<<dim3(NT_TOTAL, BB), 512, 49152, stream>>>(
      x, Wqb, bq, kvTb, Wob, bo, out);
}